// Round 3
// baseline (2385.032 us; speedup 1.0000x reference)
//
#include <hip/hip_runtime.h>
#include <math.h>

#define NN 50000
#define EE 800000
#define NPAIR 200000

__device__ __forceinline__ float leaky(float x){ return x >= 0.f ? x : 0.2f*x; }

// ---------------- degree / norms / CSR build ----------------

__global__ void degree_kernel(const int* __restrict__ src, const int* __restrict__ dst,
                              int* cnt_out, int* cnt_in){
  int i = blockIdx.x*blockDim.x + threadIdx.x;
  if(i < EE){
    atomicAdd(&cnt_out[src[i]], 1);
    atomicAdd(&cnt_in[dst[i]], 1);
  }
}

__global__ void norm_kernel(const int* __restrict__ cnt_out, const int* __restrict__ cnt_in,
                            float* __restrict__ out_norm, float* __restrict__ in_norm){
  int i = blockIdx.x*blockDim.x + threadIdx.x;
  if(i < NN){
    int o = cnt_out[i]; if(o < 1) o = 1;
    int d = cnt_in[i];  if(d < 1) d = 1;
    out_norm[i] = 1.f/sqrtf((float)o);
    in_norm[i]  = 1.f/sqrtf((float)d);
  }
}

// single-block exclusive scan of cnt_in[NN] -> row_off[NN+1]
__global__ void scan_kernel(const int* __restrict__ cnt, int* __restrict__ row_off){
  const int T = 512;
  __shared__ int sums[T];
  int t = threadIdx.x;
  int chunk = (NN + T - 1)/T;
  int base = t*chunk;
  int hi = base + chunk; if(hi > NN) hi = NN;
  int s = 0;
  for(int i = base; i < hi; i++) s += cnt[i];
  sums[t] = s;
  __syncthreads();
  for(int off = 1; off < T; off <<= 1){
    int add = (t >= off) ? sums[t-off] : 0;
    __syncthreads();
    sums[t] += add;
    __syncthreads();
  }
  int run = sums[t] - s;   // exclusive prefix of this thread's chunk
  for(int i = base; i < hi; i++){ row_off[i] = run; run += cnt[i]; }
  if(t == T-1) row_off[NN] = EE;
}

// ew2 = w * out_norm[src]: out_norm commutes with @W, so fold it into the
// edge weight once — removes the scale_rows pass and all GEMM prescales.
__global__ void bucket_kernel(const int* __restrict__ src, const int* __restrict__ dst,
                              const float* __restrict__ w, const float* __restrict__ out_norm,
                              const int* __restrict__ row_off,
                              int* fill, int* __restrict__ es, float* __restrict__ ew){
  int i = blockIdx.x*blockDim.x + threadIdx.x;
  if(i < EE){
    int d = dst[i];
    int s = src[i];
    int p = row_off[d] + atomicAdd(&fill[d], 1);
    es[p] = s;
    ew[p] = w[i] * out_norm[s];
  }
}

// ---------------- aggregation v2 (dst-CSR, float4, 4 edges in flight) ----------
// MODE 0: plain sum; MODE 1: relu(sum*in_norm[v] + bias); MODE 2: sum*in_norm[v]+bias
template<int F, int MODE>
__global__ __launch_bounds__(256) void agg_kernel(
    const float* __restrict__ feat, const int* __restrict__ es,
    const float* __restrict__ ew, const int* __restrict__ row_off,
    const float* __restrict__ innorm, const float* __restrict__ bias,
    float* __restrict__ out){
  constexpr int F4 = F/4;                 // 64 (F=256) or 40 (F=160)
  __shared__ float4 red[4*F4];
  int tid = threadIdx.x;
  int w = tid >> 6, lane = tid & 63;
  int v = blockIdx.x;
  int s = row_off[v], e = row_off[v+1];
  if(lane < F4){
    const float4* f4 = (const float4*)feat;
    float4 acc0 = {0,0,0,0}, acc1 = {0,0,0,0};
    int j = s + w;
    for(; j + 4 < e; j += 8){
      int u0 = es[j];   float w0 = ew[j];
      int u1 = es[j+4]; float w1 = ew[j+4];
      float4 a = f4[(size_t)u0*F4 + lane];
      float4 b = f4[(size_t)u1*F4 + lane];
      acc0.x += a.x*w0; acc0.y += a.y*w0; acc0.z += a.z*w0; acc0.w += a.w*w0;
      acc1.x += b.x*w1; acc1.y += b.y*w1; acc1.z += b.z*w1; acc1.w += b.w*w1;
    }
    if(j < e){
      int u = es[j]; float wt = ew[j];
      float4 a = f4[(size_t)u*F4 + lane];
      acc0.x += a.x*wt; acc0.y += a.y*wt; acc0.z += a.z*wt; acc0.w += a.w*wt;
    }
    acc0.x += acc1.x; acc0.y += acc1.y; acc0.z += acc1.z; acc0.w += acc1.w;
    red[w*F4 + lane] = acc0;
  }
  __syncthreads();
  if(tid < F4){
    float4 r0 = red[tid], r1 = red[F4+tid], r2 = red[2*F4+tid], r3 = red[3*F4+tid];
    float4 r;
    r.x = r0.x+r1.x+r2.x+r3.x;
    r.y = r0.y+r1.y+r2.y+r3.y;
    r.z = r0.z+r1.z+r2.z+r3.z;
    r.w = r0.w+r1.w+r2.w+r3.w;
    if(MODE >= 1){
      float inm = innorm[v];
      float4 bb = *(const float4*)&bias[tid*4];
      r.x = r.x*inm + bb.x; r.y = r.y*inm + bb.y;
      r.z = r.z*inm + bb.z; r.w = r.w*inm + bb.w;
      if(MODE == 1){
        r.x = fmaxf(r.x, 0.f); r.y = fmaxf(r.y, 0.f);
        r.z = fmaxf(r.z, 0.f); r.w = fmaxf(r.w, 0.f);
      }
    }
    ((float4*)(out + (size_t)v*F))[tid] = r;
  }
}

// ---------------- fp32 tiled GEMM v2: 128x128 tile, 8x8 microtile -------------
// C[N x M] = A @ B ; EPI: C = relu(C*in_norm[row] + bias[col])
template<bool EPI>
__global__ __launch_bounds__(256, 4) void gemm_kernel(
    const float* __restrict__ A, const float* __restrict__ B, float* __restrict__ C,
    int K, int M, const float* __restrict__ innorm, const float* __restrict__ bias){
  __shared__ float As[16][132];   // [k][row], +4 pad
  __shared__ float Bs[16][128];   // [k][col]
  int tid = threadIdx.x;
  int row0 = blockIdx.x*128, col0 = blockIdx.y*128;
  int arow = tid >> 1, ak = (tid & 1)*8;
  int grow = row0 + arow;
  int bcol = (tid & 31)*4, brow = tid >> 5;
  int tr = tid >> 4, tc = tid & 15;
  float acc[8][8] = {};
  const float* Arow = A + (size_t)grow*K;
  bool bvalid = (col0 + bcol + 3 < M);

  for(int k0 = 0; k0 < K; k0 += 16){
    float4 av0 = {0,0,0,0}, av1 = {0,0,0,0};
    if(grow < NN){
      av0 = *(const float4*)&Arow[k0 + ak];
      av1 = *(const float4*)&Arow[k0 + ak + 4];
    }
    float4 bv0 = {0,0,0,0}, bv1 = {0,0,0,0};
    if(bvalid){
      bv0 = *(const float4*)&B[(size_t)(k0+brow)*M + col0 + bcol];
      bv1 = *(const float4*)&B[(size_t)(k0+brow+8)*M + col0 + bcol];
    }
    __syncthreads();   // previous iter's reads done before overwrite
    As[ak+0][arow] = av0.x; As[ak+1][arow] = av0.y;
    As[ak+2][arow] = av0.z; As[ak+3][arow] = av0.w;
    As[ak+4][arow] = av1.x; As[ak+5][arow] = av1.y;
    As[ak+6][arow] = av1.z; As[ak+7][arow] = av1.w;
    *(float4*)&Bs[brow][bcol]   = bv0;
    *(float4*)&Bs[brow+8][bcol] = bv1;
    __syncthreads();
    #pragma unroll
    for(int k = 0; k < 16; k++){
      float4 a0 = *(const float4*)&As[k][tr*8];
      float4 a1 = *(const float4*)&As[k][tr*8 + 4];
      float4 b0 = *(const float4*)&Bs[k][tc*8];
      float4 b1 = *(const float4*)&Bs[k][tc*8 + 4];
      float a[8] = {a0.x,a0.y,a0.z,a0.w,a1.x,a1.y,a1.z,a1.w};
      float b[8] = {b0.x,b0.y,b0.z,b0.w,b1.x,b1.y,b1.z,b1.w};
      #pragma unroll
      for(int i = 0; i < 8; i++)
        #pragma unroll
        for(int j = 0; j < 8; j++)
          acc[i][j] += a[i]*b[j];
    }
  }

  bool fullc = (col0 + 128 <= M);
  #pragma unroll
  for(int i = 0; i < 8; i++){
    int r = row0 + tr*8 + i;
    if(r >= NN) continue;
    float inm = EPI ? innorm[r] : 1.f;
    int c0 = col0 + tc*8;
    float vals[8];
    #pragma unroll
    for(int j = 0; j < 8; j++){
      float vv = acc[i][j];
      if(EPI){ vv = fmaxf(vv*inm + bias[c0 + j], 0.f); }
      vals[j] = vv;
    }
    if(fullc){
      *(float4*)&C[(size_t)r*M + c0]     = make_float4(vals[0],vals[1],vals[2],vals[3]);
      *(float4*)&C[(size_t)r*M + c0 + 4] = make_float4(vals[4],vals[5],vals[6],vals[7]);
    }else{
      #pragma unroll
      for(int j = 0; j < 8; j++){
        int c = c0 + j;
        if(c < M) C[(size_t)r*M + c] = vals[j];
      }
    }
  }
}

// ---------------- predictor: fused tiled GEMM, 64 pairs/block ----------------
// LDS 53760 B (3 blocks/CU):
//   phase A: z^T [160][68-stride] (43520 B), P1 k-panel [32][80] @10880 floats
//   phase B: y1^T [80][65] @0, P2 [80][40] @5200, y2^T [40][65] @8400
#define ZS 68   // z row stride: 68%32=4 -> stores 2-way max (free); 272B rows keep b128 align
__global__ __launch_bounds__(256) void predictor_kernel(
    const float* __restrict__ h3, const int* __restrict__ ps, const int* __restrict__ pd,
    const int* __restrict__ ns, const int* __restrict__ nd,
    const float* __restrict__ P1, const float* __restrict__ pb1,
    const float* __restrict__ P2, const float* __restrict__ pb2,
    const float* __restrict__ P3, const float* __restrict__ pb3,
    float* __restrict__ out){
  __shared__ float smem[13440];
  float* z   = smem;            // [160][ZS]
  float* p1p = smem + 160*ZS;   // [32][80]
  float* y1  = smem;            // [80][65]
  float* p2  = smem + 5200;     // [80][40]
  float* y2  = smem + 8400;     // [40][65]
  int tid = threadIdx.x;
  int pair0 = blockIdx.x*64;    // grid = 2*NPAIR/64 exactly

  // --- gather h3 rows, z[k][p] = ha[k]*hb[k] (transposed, conflict-free) ---
  {
    int p = tid >> 2, sub = tid & 3;
    int q = pair0 + p;
    int a, b;
    if(q < NPAIR){ a = ps[q]; b = pd[q]; }
    else         { a = ns[q-NPAIR]; b = nd[q-NPAIR]; }
    const float4* ra = (const float4*)(h3 + (size_t)a*160);
    const float4* rb = (const float4*)(h3 + (size_t)b*160);
    #pragma unroll
    for(int it = 0; it < 10; it++){
      int g = sub + it*4;            // interleaved k-groups: banks 2-way max
      float4 va = ra[g], vb = rb[g];
      int k = g*4;
      z[(k+0)*ZS + p] = va.x*vb.x;
      z[(k+1)*ZS + p] = va.y*vb.y;
      z[(k+2)*ZS + p] = va.z*vb.z;
      z[(k+3)*ZS + p] = va.w*vb.w;
    }
  }

  // --- stage 1: y1[64 pairs][80 cols] = leaky(z @ P1 + pb1) ---
  int tr = tid >> 4, tc = tid & 15;       // thread: pairs tr*4..+3, cols tc+16j
  float acc1[4][5];
  #pragma unroll
  for(int j = 0; j < 5; j++){
    float bv = pb1[tc + 16*j];
    #pragma unroll
    for(int i = 0; i < 4; i++) acc1[i][j] = bv;
  }
  for(int k0 = 0; k0 < 160; k0 += 32){
    __syncthreads();                       // z ready / p1p free
    const float4* gp = (const float4*)(P1 + k0*80);
    for(int i = tid; i < 640; i += 256) ((float4*)p1p)[i] = gp[i];
    __syncthreads();
    #pragma unroll 8
    for(int kk = 0; kk < 32; kk++){
      float4 av = *(const float4*)&z[(k0+kk)*ZS + tr*4];
      float a0 = av.x, a1 = av.y, a2 = av.z, a3 = av.w;
      float b[5];
      #pragma unroll
      for(int j = 0; j < 5; j++) b[j] = p1p[kk*80 + tc + 16*j];
      #pragma unroll
      for(int j = 0; j < 5; j++){
        acc1[0][j] += a0*b[j];
        acc1[1][j] += a1*b[j];
        acc1[2][j] += a2*b[j];
        acc1[3][j] += a3*b[j];
      }
    }
  }
  __syncthreads();                          // all z reads done; region reusable

  // write y1^T (padded 65), stage P2
  #pragma unroll
  for(int i = 0; i < 4; i++)
    #pragma unroll
    for(int j = 0; j < 5; j++)
      y1[(tc + 16*j)*65 + tr*4 + i] = leaky(acc1[i][j]);
  for(int i = tid; i < 800; i += 256) ((float4*)p2)[i] = ((const float4*)P2)[i];
  __syncthreads();

  // --- stage 2: y2[64][40] = leaky(y1 @ P2 + pb2); thread: 2 pairs x 5 cols ---
  int tr2 = tid >> 3, tc2 = tid & 7;       // pairs tr2*2..+1, cols tc2+8j
  float acc2[2][5];
  #pragma unroll
  for(int j = 0; j < 5; j++){
    float bv = pb2[tc2 + 8*j];
    acc2[0][j] = bv; acc2[1][j] = bv;
  }
  #pragma unroll 4
  for(int k = 0; k < 80; k++){
    float a0 = y1[k*65 + tr2*2], a1 = y1[k*65 + tr2*2 + 1];
    #pragma unroll
    for(int j = 0; j < 5; j++){
      float bv = p2[k*40 + tc2 + 8*j];
      acc2[0][j] += a0*bv;
      acc2[1][j] += a1*bv;
    }
  }
  #pragma unroll
  for(int i = 0; i < 2; i++)
    #pragma unroll
    for(int j = 0; j < 5; j++)
      y2[(tc2 + 8*j)*65 + tr2*2 + i] = leaky(acc2[i][j]);
  __syncthreads();

  // --- stage 3: out[p] = y2[p] . P3 + pb3 ---
  if(tid < 64){
    float s = pb3[0];
    #pragma unroll 8
    for(int k = 0; k < 40; k++) s += y2[k*65 + tid]*P3[k];
    out[pair0 + tid] = s;
  }
}

// ---------------- launch ----------------

extern "C" void kernel_launch(void* const* d_in, const int* in_sizes, int n_in,
                              void* d_out, int out_size, void* d_ws, size_t ws_size,
                              hipStream_t stream) {
  const float* x  = (const float*)d_in[0];
  const float* w  = (const float*)d_in[1];
  const int* src  = (const int*)d_in[2];
  const int* dst  = (const int*)d_in[3];
  const int* ps   = (const int*)d_in[4];
  const int* pd   = (const int*)d_in[5];
  const int* ns   = (const int*)d_in[6];
  const int* nd   = (const int*)d_in[7];
  const float* W1 = (const float*)d_in[8];  const float* b1  = (const float*)d_in[9];
  const float* W2 = (const float*)d_in[10]; const float* b2  = (const float*)d_in[11];
  const float* W3 = (const float*)d_in[12]; const float* b3  = (const float*)d_in[13];
  const float* P1 = (const float*)d_in[14]; const float* pb1 = (const float*)d_in[15];
  const float* P2 = (const float*)d_in[16]; const float* pb2 = (const float*)d_in[17];
  const float* P3 = (const float*)d_in[18]; const float* pb3 = (const float*)d_in[19];
  float* out = (float*)d_out;

  char* p = (char*)d_ws;
  auto alloc = [&](size_t bytes)->char*{
    char* r = p; p += (bytes + 255) & ~(size_t)255; return r;
  };
  int*   cnt_out = (int*)  alloc(NN*4);          // these three must stay contiguous
  int*   cnt_in  = (int*)  alloc(NN*4);          // (zeroed with one memset)
  int*   fill    = (int*)  alloc(NN*4);
  int*   row_off = (int*)  alloc((NN+1)*4);
  float* out_nrm = (float*)alloc(NN*4);
  float* in_nrm  = (float*)alloc(NN*4);
  int*   es      = (int*)  alloc((size_t)EE*4);
  float* ew      = (float*)alloc((size_t)EE*4);
  float* bufA    = (float*)alloc((size_t)NN*512*4);  // h1 (N x 512)
  float* bufB    = (float*)alloc((size_t)NN*256*4);  // proj2 / proj3
  float* bufC    = (float*)alloc((size_t)NN*256*4);  // agg1 / h2

  size_t cntPad = (NN*4 + 255) & ~(size_t)255;
  hipMemsetAsync(cnt_out, 0, 3*cntPad, stream);

  degree_kernel<<<(EE+255)/256, 256, 0, stream>>>(src, dst, cnt_out, cnt_in);
  norm_kernel<<<(NN+255)/256, 256, 0, stream>>>(cnt_out, cnt_in, out_nrm, in_nrm);
  scan_kernel<<<1, 512, 0, stream>>>(cnt_in, row_off);
  bucket_kernel<<<(EE+255)/256, 256, 0, stream>>>(src, dst, w, out_nrm, row_off, fill, es, ew);

  dim3 gA(391, 4), gB(391, 2);

  // layer 1: agg(x, ew2) @ W1, epilogue relu(*in_norm + b1)
  agg_kernel<256,0><<<NN, 256, 0, stream>>>(x, es, ew, row_off, nullptr, nullptr, bufC);
  gemm_kernel<true><<<gA, 256, 0, stream>>>(bufC, W1, bufA, 256, 512, in_nrm, b1);

  // layer 2: agg(h1 @ W2, ew2), fused epilogue relu(*in_norm + b2)
  gemm_kernel<false><<<gB, 256, 0, stream>>>(bufA, W2, bufB, 512, 256, nullptr, nullptr);
  agg_kernel<256,1><<<NN, 256, 0, stream>>>(bufB, es, ew, row_off, in_nrm, b2, bufC);

  // layer 3: agg(h2 @ W3, ew2), fused epilogue *in_norm + b3 -> d_out h region
  gemm_kernel<false><<<gB, 256, 0, stream>>>(bufC, W3, bufB, 256, 160, nullptr, nullptr);
  agg_kernel<160,2><<<NN, 256, 0, stream>>>(bufB, es, ew, row_off, in_nrm, b3, out + 2*NPAIR);

  // predictor on pos+neg pairs
  predictor_kernel<<<(2*NPAIR)/64, 256, 0, stream>>>(out + 2*NPAIR, ps, pd, ns, nd,
                                                     P1, pb1, P2, pb2, P3, pb3, out);
}

// Round 4
// 1318.321 us; speedup vs baseline: 1.8091x; 1.8091x over previous
//
#include <hip/hip_runtime.h>
#include <math.h>

#define NN 50000
#define EE 800000
#define NPAIR 200000

__device__ __forceinline__ float leaky(float x){ return x >= 0.f ? x : 0.2f*x; }

// ---------------- degree / norms / CSR build ----------------

__global__ void degree_kernel(const int* __restrict__ src, const int* __restrict__ dst,
                              int* cnt_out, int* cnt_in){
  int i = blockIdx.x*blockDim.x + threadIdx.x;
  if(i < EE){
    atomicAdd(&cnt_out[src[i]], 1);
    atomicAdd(&cnt_in[dst[i]], 1);
  }
}

__global__ void norm_kernel(const int* __restrict__ cnt_out, const int* __restrict__ cnt_in,
                            float* __restrict__ out_norm, float* __restrict__ in_norm){
  int i = blockIdx.x*blockDim.x + threadIdx.x;
  if(i < NN){
    int o = cnt_out[i]; if(o < 1) o = 1;
    int d = cnt_in[i];  if(d < 1) d = 1;
    out_norm[i] = 1.f/sqrtf((float)o);
    in_norm[i]  = 1.f/sqrtf((float)d);
  }
}

// single-block exclusive scan of cnt_in[NN] -> row_off[NN+1]
__global__ void scan_kernel(const int* __restrict__ cnt, int* __restrict__ row_off){
  const int T = 512;
  __shared__ int sums[T];
  int t = threadIdx.x;
  int chunk = (NN + T - 1)/T;
  int base = t*chunk;
  int hi = base + chunk; if(hi > NN) hi = NN;
  int s = 0;
  for(int i = base; i < hi; i++) s += cnt[i];
  sums[t] = s;
  __syncthreads();
  for(int off = 1; off < T; off <<= 1){
    int add = (t >= off) ? sums[t-off] : 0;
    __syncthreads();
    sums[t] += add;
    __syncthreads();
  }
  int run = sums[t] - s;   // exclusive prefix of this thread's chunk
  for(int i = base; i < hi; i++){ row_off[i] = run; run += cnt[i]; }
  if(t == T-1) row_off[NN] = EE;
}

// ew2 = w * out_norm[src]: out_norm commutes with @W, so fold it into the
// edge weight once — removes the scale_rows pass and all GEMM prescales.
__global__ void bucket_kernel(const int* __restrict__ src, const int* __restrict__ dst,
                              const float* __restrict__ w, const float* __restrict__ out_norm,
                              const int* __restrict__ row_off,
                              int* fill, int* __restrict__ es, float* __restrict__ ew){
  int i = blockIdx.x*blockDim.x + threadIdx.x;
  if(i < EE){
    int d = dst[i];
    int s = src[i];
    int p = row_off[d] + atomicAdd(&fill[d], 1);
    es[p] = s;
    ew[p] = w[i] * out_norm[s];
  }
}

// ---------------- aggregation v2 (dst-CSR, float4, 4 edges in flight) ----------
// MODE 0: plain sum; MODE 1: relu(sum*in_norm[v] + bias); MODE 2: sum*in_norm[v]+bias
template<int F, int MODE>
__global__ __launch_bounds__(256) void agg_kernel(
    const float* __restrict__ feat, const int* __restrict__ es,
    const float* __restrict__ ew, const int* __restrict__ row_off,
    const float* __restrict__ innorm, const float* __restrict__ bias,
    float* __restrict__ out){
  constexpr int F4 = F/4;                 // 64 (F=256) or 40 (F=160)
  __shared__ float4 red[4*F4];
  int tid = threadIdx.x;
  int w = tid >> 6, lane = tid & 63;
  int v = blockIdx.x;
  int s = row_off[v], e = row_off[v+1];
  if(lane < F4){
    const float4* f4 = (const float4*)feat;
    float4 acc0 = {0,0,0,0}, acc1 = {0,0,0,0};
    int j = s + w;
    for(; j + 4 < e; j += 8){
      int u0 = es[j];   float w0 = ew[j];
      int u1 = es[j+4]; float w1 = ew[j+4];
      float4 a = f4[(size_t)u0*F4 + lane];
      float4 b = f4[(size_t)u1*F4 + lane];
      acc0.x += a.x*w0; acc0.y += a.y*w0; acc0.z += a.z*w0; acc0.w += a.w*w0;
      acc1.x += b.x*w1; acc1.y += b.y*w1; acc1.z += b.z*w1; acc1.w += b.w*w1;
    }
    if(j < e){
      int u = es[j]; float wt = ew[j];
      float4 a = f4[(size_t)u*F4 + lane];
      acc0.x += a.x*wt; acc0.y += a.y*wt; acc0.z += a.z*wt; acc0.w += a.w*wt;
    }
    acc0.x += acc1.x; acc0.y += acc1.y; acc0.z += acc1.z; acc0.w += acc1.w;
    red[w*F4 + lane] = acc0;
  }
  __syncthreads();
  if(tid < F4){
    float4 r0 = red[tid], r1 = red[F4+tid], r2 = red[2*F4+tid], r3 = red[3*F4+tid];
    float4 r;
    r.x = r0.x+r1.x+r2.x+r3.x;
    r.y = r0.y+r1.y+r2.y+r3.y;
    r.z = r0.z+r1.z+r2.z+r3.z;
    r.w = r0.w+r1.w+r2.w+r3.w;
    if(MODE >= 1){
      float inm = innorm[v];
      float4 bb = *(const float4*)&bias[tid*4];
      r.x = r.x*inm + bb.x; r.y = r.y*inm + bb.y;
      r.z = r.z*inm + bb.z; r.w = r.w*inm + bb.w;
      if(MODE == 1){
        r.x = fmaxf(r.x, 0.f); r.y = fmaxf(r.y, 0.f);
        r.z = fmaxf(r.z, 0.f); r.w = fmaxf(r.w, 0.f);
      }
    }
    ((float4*)(out + (size_t)v*F))[tid] = r;
  }
}

// ---------------- fp32 tiled GEMM v2: 128x128 tile, 8x8 microtile -------------
// C[N x M] = A @ B ; EPI: C = relu(C*in_norm[row] + bias[col])
// NOTE: no min-waves clamp — (256,4) forced a 64-VGPR cap and spilled the
// 8x8 accumulator to scratch (R3: 3.7 GB HBM traffic/dispatch, 950 us).
template<bool EPI>
__global__ __launch_bounds__(256) void gemm_kernel(
    const float* __restrict__ A, const float* __restrict__ B, float* __restrict__ C,
    int K, int M, const float* __restrict__ innorm, const float* __restrict__ bias){
  __shared__ float As[16][132];   // [k][row], +4 pad
  __shared__ float Bs[16][128];   // [k][col]
  int tid = threadIdx.x;
  int row0 = blockIdx.x*128, col0 = blockIdx.y*128;
  int arow = tid >> 1, ak = (tid & 1)*8;
  int grow = row0 + arow;
  int bcol = (tid & 31)*4, brow = tid >> 5;
  int tr = tid >> 4, tc = tid & 15;
  float acc[8][8] = {};
  const float* Arow = A + (size_t)grow*K;
  bool bvalid = (col0 + bcol + 3 < M);

  for(int k0 = 0; k0 < K; k0 += 16){
    float4 av0 = {0,0,0,0}, av1 = {0,0,0,0};
    if(grow < NN){
      av0 = *(const float4*)&Arow[k0 + ak];
      av1 = *(const float4*)&Arow[k0 + ak + 4];
    }
    float4 bv0 = {0,0,0,0}, bv1 = {0,0,0,0};
    if(bvalid){
      bv0 = *(const float4*)&B[(size_t)(k0+brow)*M + col0 + bcol];
      bv1 = *(const float4*)&B[(size_t)(k0+brow+8)*M + col0 + bcol];
    }
    __syncthreads();   // previous iter's reads done before overwrite
    As[ak+0][arow] = av0.x; As[ak+1][arow] = av0.y;
    As[ak+2][arow] = av0.z; As[ak+3][arow] = av0.w;
    As[ak+4][arow] = av1.x; As[ak+5][arow] = av1.y;
    As[ak+6][arow] = av1.z; As[ak+7][arow] = av1.w;
    *(float4*)&Bs[brow][bcol]   = bv0;
    *(float4*)&Bs[brow+8][bcol] = bv1;
    __syncthreads();
    #pragma unroll
    for(int k = 0; k < 16; k++){
      float4 a0 = *(const float4*)&As[k][tr*8];
      float4 a1 = *(const float4*)&As[k][tr*8 + 4];
      float4 b0 = *(const float4*)&Bs[k][tc*8];
      float4 b1 = *(const float4*)&Bs[k][tc*8 + 4];
      float a[8] = {a0.x,a0.y,a0.z,a0.w,a1.x,a1.y,a1.z,a1.w};
      float b[8] = {b0.x,b0.y,b0.z,b0.w,b1.x,b1.y,b1.z,b1.w};
      #pragma unroll
      for(int i = 0; i < 8; i++)
        #pragma unroll
        for(int j = 0; j < 8; j++)
          acc[i][j] += a[i]*b[j];
    }
  }

  bool fullc = (col0 + 128 <= M);
  #pragma unroll
  for(int i = 0; i < 8; i++){
    int r = row0 + tr*8 + i;
    if(r >= NN) continue;
    float inm = EPI ? innorm[r] : 1.f;
    int c0 = col0 + tc*8;
    float vals[8];
    #pragma unroll
    for(int j = 0; j < 8; j++){
      float vv = acc[i][j];
      if(EPI){ vv = fmaxf(vv*inm + bias[c0 + j], 0.f); }
      vals[j] = vv;
    }
    if(fullc){
      *(float4*)&C[(size_t)r*M + c0]     = make_float4(vals[0],vals[1],vals[2],vals[3]);
      *(float4*)&C[(size_t)r*M + c0 + 4] = make_float4(vals[4],vals[5],vals[6],vals[7]);
    }else{
      #pragma unroll
      for(int j = 0; j < 8; j++){
        int c = c0 + j;
        if(c < M) C[(size_t)r*M + c] = vals[j];
      }
    }
  }
}

// ---------------- predictor: fused tiled GEMM, 64 pairs/block ----------------
// LDS 53760 B (3 blocks/CU):
//   phase A: z^T [160][68-stride] (43520 B), P1 k-panel [32][80] @10880 floats
//   phase B: y1^T [80][65] @0, P2 [80][40] @5200, y2^T [40][65] @8400
#define ZS 68   // z row stride: 68%32=4 -> stores 2-way max (free); 272B rows keep b128 align
__global__ __launch_bounds__(256) void predictor_kernel(
    const float* __restrict__ h3, const int* __restrict__ ps, const int* __restrict__ pd,
    const int* __restrict__ ns, const int* __restrict__ nd,
    const float* __restrict__ P1, const float* __restrict__ pb1,
    const float* __restrict__ P2, const float* __restrict__ pb2,
    const float* __restrict__ P3, const float* __restrict__ pb3,
    float* __restrict__ out){
  __shared__ float smem[13440];
  float* z   = smem;            // [160][ZS]
  float* p1p = smem + 160*ZS;   // [32][80]
  float* y1  = smem;            // [80][65]
  float* p2  = smem + 5200;     // [80][40]
  float* y2  = smem + 8400;     // [40][65]
  int tid = threadIdx.x;
  int pair0 = blockIdx.x*64;    // grid = 2*NPAIR/64 exactly

  // --- gather h3 rows, z[k][p] = ha[k]*hb[k] (transposed, conflict-free) ---
  {
    int p = tid >> 2, sub = tid & 3;
    int q = pair0 + p;
    int a, b;
    if(q < NPAIR){ a = ps[q]; b = pd[q]; }
    else         { a = ns[q-NPAIR]; b = nd[q-NPAIR]; }
    const float4* ra = (const float4*)(h3 + (size_t)a*160);
    const float4* rb = (const float4*)(h3 + (size_t)b*160);
    #pragma unroll
    for(int it = 0; it < 10; it++){
      int g = sub + it*4;            // interleaved k-groups: banks 2-way max
      float4 va = ra[g], vb = rb[g];
      int k = g*4;
      z[(k+0)*ZS + p] = va.x*vb.x;
      z[(k+1)*ZS + p] = va.y*vb.y;
      z[(k+2)*ZS + p] = va.z*vb.z;
      z[(k+3)*ZS + p] = va.w*vb.w;
    }
  }

  // --- stage 1: y1[64 pairs][80 cols] = leaky(z @ P1 + pb1) ---
  int tr = tid >> 4, tc = tid & 15;       // thread: pairs tr*4..+3, cols tc+16j
  float acc1[4][5];
  #pragma unroll
  for(int j = 0; j < 5; j++){
    float bv = pb1[tc + 16*j];
    #pragma unroll
    for(int i = 0; i < 4; i++) acc1[i][j] = bv;
  }
  for(int k0 = 0; k0 < 160; k0 += 32){
    __syncthreads();                       // z ready / p1p free
    const float4* gp = (const float4*)(P1 + k0*80);
    for(int i = tid; i < 640; i += 256) ((float4*)p1p)[i] = gp[i];
    __syncthreads();
    #pragma unroll 8
    for(int kk = 0; kk < 32; kk++){
      float4 av = *(const float4*)&z[(k0+kk)*ZS + tr*4];
      float a0 = av.x, a1 = av.y, a2 = av.z, a3 = av.w;
      float b[5];
      #pragma unroll
      for(int j = 0; j < 5; j++) b[j] = p1p[kk*80 + tc + 16*j];
      #pragma unroll
      for(int j = 0; j < 5; j++){
        acc1[0][j] += a0*b[j];
        acc1[1][j] += a1*b[j];
        acc1[2][j] += a2*b[j];
        acc1[3][j] += a3*b[j];
      }
    }
  }
  __syncthreads();                          // all z reads done; region reusable

  // write y1^T (padded 65), stage P2
  #pragma unroll
  for(int i = 0; i < 4; i++)
    #pragma unroll
    for(int j = 0; j < 5; j++)
      y1[(tc + 16*j)*65 + tr*4 + i] = leaky(acc1[i][j]);
  for(int i = tid; i < 800; i += 256) ((float4*)p2)[i] = ((const float4*)P2)[i];
  __syncthreads();

  // --- stage 2: y2[64][40] = leaky(y1 @ P2 + pb2); thread: 2 pairs x 5 cols ---
  int tr2 = tid >> 3, tc2 = tid & 7;       // pairs tr2*2..+1, cols tc2+8j
  float acc2[2][5];
  #pragma unroll
  for(int j = 0; j < 5; j++){
    float bv = pb2[tc2 + 8*j];
    acc2[0][j] = bv; acc2[1][j] = bv;
  }
  #pragma unroll 4
  for(int k = 0; k < 80; k++){
    float a0 = y1[k*65 + tr2*2], a1 = y1[k*65 + tr2*2 + 1];
    #pragma unroll
    for(int j = 0; j < 5; j++){
      float bv = p2[k*40 + tc2 + 8*j];
      acc2[0][j] += a0*bv;
      acc2[1][j] += a1*bv;
    }
  }
  #pragma unroll
  for(int i = 0; i < 2; i++)
    #pragma unroll
    for(int j = 0; j < 5; j++)
      y2[(tc2 + 8*j)*65 + tr2*2 + i] = leaky(acc2[i][j]);
  __syncthreads();

  // --- stage 3: out[p] = y2[p] . P3 + pb3 ---
  if(tid < 64){
    float s = pb3[0];
    #pragma unroll 8
    for(int k = 0; k < 40; k++) s += y2[k*65 + tid]*P3[k];
    out[pair0 + tid] = s;
  }
}

// ---------------- launch ----------------

extern "C" void kernel_launch(void* const* d_in, const int* in_sizes, int n_in,
                              void* d_out, int out_size, void* d_ws, size_t ws_size,
                              hipStream_t stream) {
  const float* x  = (const float*)d_in[0];
  const float* w  = (const float*)d_in[1];
  const int* src  = (const int*)d_in[2];
  const int* dst  = (const int*)d_in[3];
  const int* ps   = (const int*)d_in[4];
  const int* pd   = (const int*)d_in[5];
  const int* ns   = (const int*)d_in[6];
  const int* nd   = (const int*)d_in[7];
  const float* W1 = (const float*)d_in[8];  const float* b1  = (const float*)d_in[9];
  const float* W2 = (const float*)d_in[10]; const float* b2  = (const float*)d_in[11];
  const float* W3 = (const float*)d_in[12]; const float* b3  = (const float*)d_in[13];
  const float* P1 = (const float*)d_in[14]; const float* pb1 = (const float*)d_in[15];
  const float* P2 = (const float*)d_in[16]; const float* pb2 = (const float*)d_in[17];
  const float* P3 = (const float*)d_in[18]; const float* pb3 = (const float*)d_in[19];
  float* out = (float*)d_out;

  char* p = (char*)d_ws;
  auto alloc = [&](size_t bytes)->char*{
    char* r = p; p += (bytes + 255) & ~(size_t)255; return r;
  };
  int*   cnt_out = (int*)  alloc(NN*4);          // these three must stay contiguous
  int*   cnt_in  = (int*)  alloc(NN*4);          // (zeroed with one memset)
  int*   fill    = (int*)  alloc(NN*4);
  int*   row_off = (int*)  alloc((NN+1)*4);
  float* out_nrm = (float*)alloc(NN*4);
  float* in_nrm  = (float*)alloc(NN*4);
  int*   es      = (int*)  alloc((size_t)EE*4);
  float* ew      = (float*)alloc((size_t)EE*4);
  float* bufA    = (float*)alloc((size_t)NN*512*4);  // h1 (N x 512)
  float* bufB    = (float*)alloc((size_t)NN*256*4);  // proj2 / proj3
  float* bufC    = (float*)alloc((size_t)NN*256*4);  // agg1 / h2

  size_t cntPad = (NN*4 + 255) & ~(size_t)255;
  hipMemsetAsync(cnt_out, 0, 3*cntPad, stream);

  degree_kernel<<<(EE+255)/256, 256, 0, stream>>>(src, dst, cnt_out, cnt_in);
  norm_kernel<<<(NN+255)/256, 256, 0, stream>>>(cnt_out, cnt_in, out_nrm, in_nrm);
  scan_kernel<<<1, 512, 0, stream>>>(cnt_in, row_off);
  bucket_kernel<<<(EE+255)/256, 256, 0, stream>>>(src, dst, w, out_nrm, row_off, fill, es, ew);

  dim3 gA(391, 4), gB(391, 2);

  // layer 1: agg(x, ew2) @ W1, epilogue relu(*in_norm + b1)
  agg_kernel<256,0><<<NN, 256, 0, stream>>>(x, es, ew, row_off, nullptr, nullptr, bufC);
  gemm_kernel<true><<<gA, 256, 0, stream>>>(bufC, W1, bufA, 256, 512, in_nrm, b1);

  // layer 2: agg(h1 @ W2, ew2), fused epilogue relu(*in_norm + b2)
  gemm_kernel<false><<<gB, 256, 0, stream>>>(bufA, W2, bufB, 512, 256, nullptr, nullptr);
  agg_kernel<256,1><<<NN, 256, 0, stream>>>(bufB, es, ew, row_off, in_nrm, b2, bufC);

  // layer 3: agg(h2 @ W3, ew2), fused epilogue *in_norm + b3 -> d_out h region
  gemm_kernel<false><<<gB, 256, 0, stream>>>(bufC, W3, bufB, 256, 160, nullptr, nullptr);
  agg_kernel<160,2><<<NN, 256, 0, stream>>>(bufB, es, ew, row_off, in_nrm, b3, out + 2*NPAIR);

  // predictor on pos+neg pairs
  predictor_kernel<<<(2*NPAIR)/64, 256, 0, stream>>>(out + 2*NPAIR, ps, pd, ns, nd,
                                                     P1, pb1, P2, pb2, P3, pb3, out);
}